// Round 6
// baseline (238.708 us; speedup 1.0000x reference)
//
#include <hip/hip_runtime.h>
#include <hip/hip_bf16.h>

#define NN 50000
#define EE 800000
#define HH 4
#define HDIM 128   // H*D

typedef __attribute__((ext_vector_type(8))) short bf16x8;
typedef __attribute__((ext_vector_type(4))) float f32x4;

__device__ inline unsigned short f2bf(float f) {
    unsigned u = __float_as_uint(f);
    u = u + 0x7FFFu + ((u >> 16) & 1u);   // round-to-nearest-even
    return (unsigned short)(u >> 16);
}
__device__ inline float bfl(unsigned u) { return __uint_as_float(u << 16); }
__device__ inline float bfh(unsigned u) { return __uint_as_float(u & 0xFFFF0000u); }

// ---------------- K1: MFMA bf16 GEMM: h16 = bf16(feat @ fc_w^T), out = feat @ res_w^T (f32)
// grid (3125, 4): 16 rows x 64 cols per block; 4 waves, one 16x16 tile each.
__global__ __launch_bounds__(256) void mfma_gemm_kernel(const float* __restrict__ feat,
                                                        const float* __restrict__ fc_w,
                                                        const float* __restrict__ res_w,
                                                        unsigned short* __restrict__ h16,
                                                        float* __restrict__ out) {
    __shared__ float ld[16][65];
    int r0 = blockIdx.x * 16;
    int colblk = blockIdx.y;                 // 0,1 -> fc (h); 2,3 -> res (out)
    int t = threadIdx.x;
    int w = t >> 6;
    int l = t & 63;
    int l15 = l & 15;
    int kg = l >> 4;                         // 0..3
    int col = colblk * 64 + w * 16 + l15;    // 0..255
    const float* wrow = (col < 128) ? &fc_w[(size_t)col * 128]
                                    : &res_w[(size_t)(col - 128) * 128];
    const float* arow = &feat[(size_t)(r0 + l15) * 128];

    f32x4 acc = {0.f, 0.f, 0.f, 0.f};
    #pragma unroll
    for (int kk = 0; kk < 128; kk += 32) {
        int kb = kk + kg * 8;
        float4 af0 = *(const float4*)&arow[kb];
        float4 af1 = *(const float4*)&arow[kb + 4];
        float4 bw0 = *(const float4*)&wrow[kb];
        float4 bw1 = *(const float4*)&wrow[kb + 4];
        bf16x8 a, b;
        a[0] = (short)f2bf(af0.x); a[1] = (short)f2bf(af0.y);
        a[2] = (short)f2bf(af0.z); a[3] = (short)f2bf(af0.w);
        a[4] = (short)f2bf(af1.x); a[5] = (short)f2bf(af1.y);
        a[6] = (short)f2bf(af1.z); a[7] = (short)f2bf(af1.w);
        b[0] = (short)f2bf(bw0.x); b[1] = (short)f2bf(bw0.y);
        b[2] = (short)f2bf(bw0.z); b[3] = (short)f2bf(bw0.w);
        b[4] = (short)f2bf(bw1.x); b[5] = (short)f2bf(bw1.y);
        b[6] = (short)f2bf(bw1.z); b[7] = (short)f2bf(bw1.w);
        acc = __builtin_amdgcn_mfma_f32_16x16x32_bf16(a, b, acc, 0, 0, 0);
    }
    // C/D layout: col = l&15, row = 4*(l>>4)+reg  [m89]
    #pragma unroll
    for (int r = 0; r < 4; ++r)
        ld[kg * 4 + r][w * 16 + l15] = acc[r];
    __syncthreads();

    if (colblk < 2) {        // h half -> bf16, coalesced 16B stores
        if (t < 128) {
            int row = t >> 3;
            int seg = t & 7;
            unsigned short tmp[8];
            #pragma unroll
            for (int j = 0; j < 8; ++j) tmp[j] = f2bf(ld[row][seg * 8 + j]);
            *(uint4*)&h16[(size_t)(r0 + row) * 128 + colblk * 64 + seg * 8] = *(uint4*)tmp;
        }
    } else {                 // residual half -> f32 out, coalesced float4
        int row = t >> 4;
        int seg = t & 15;
        float4 v = make_float4(ld[row][seg * 4 + 0], ld[row][seg * 4 + 1],
                               ld[row][seg * 4 + 2], ld[row][seg * 4 + 3]);
        *(float4*)&out[(size_t)(r0 + row) * 128 + (colblk - 2) * 64 + seg * 4] = v;
    }
}

// ---------------- K2: el/er from bf16 h
__global__ void elr_kernel(const unsigned short* __restrict__ h16,
                           const float* __restrict__ al,
                           const float* __restrict__ ar,
                           float* __restrict__ el,
                           float* __restrict__ er,
                           int n) {
    int idx = blockIdx.x * 256 + threadIdx.x;
    int node = idx >> 7;
    if (node >= n) return;
    int hd = idx & 127;
    float v = bfl((unsigned)h16[(size_t)node * 128 + hd]);
    float a = v * al[hd];
    float b = v * ar[hd];
    #pragma unroll
    for (int off = 16; off > 0; off >>= 1) {
        a += __shfl_down(a, off, 32);
        b += __shfl_down(b, off, 32);
    }
    if ((hd & 31) == 0) {
        el[node * 4 + (hd >> 5)] = a;
        er[node * 4 + (hd >> 5)] = b;
    }
}

// ---------------- K3: degree histogram
__global__ void count_kernel(const int* __restrict__ dst,
                             int* __restrict__ cnt,
                             int e) {
    int ed = blockIdx.x * 256 + threadIdx.x;
    if (ed >= e) return;
    atomicAdd(&cnt[dst[ed]], 1);
}

// ---------------- K4: per-node segment base via wave prefix + one atomic per wave
__global__ void seg_alloc_kernel(const int* __restrict__ cnt,
                                 int* __restrict__ base,
                                 int* __restrict__ cursor,
                                 int* __restrict__ total,
                                 int n) {
    int idx = blockIdx.x * 256 + threadIdx.x;
    int lane = threadIdx.x & 63;
    int c = (idx < n) ? cnt[idx] : 0;
    int pre = c;
    #pragma unroll
    for (int d = 1; d < 64; d <<= 1) {
        int v = __shfl_up(pre, d, 64);
        if (lane >= d) pre += v;
    }
    int wtot = __shfl(pre, 63, 64);
    int wbase = 0;
    if (lane == 63) wbase = atomicAdd(total, wtot);
    wbase = __shfl(wbase, 63, 64);
    if (idx < n) {
        int b = wbase + pre - c;
        base[idx] = b;
        cursor[idx] = b;
    }
}

// ---------------- K5: per-edge score + scatter one 16B record {src, bf16 c[4]}
__global__ void edge_scatter_kernel(const int* __restrict__ src,
                                    const int* __restrict__ dst,
                                    const float* __restrict__ el,
                                    const float* __restrict__ er,
                                    int* __restrict__ cursor,
                                    uint4* __restrict__ recs,
                                    int e) {
    int ed = blockIdx.x * 256 + threadIdx.x;
    if (ed >= e) return;
    int s = src[ed];
    int d = dst[ed];
    float4 a = *(const float4*)&el[(size_t)s * 4];
    float4 b = *(const float4*)&er[(size_t)d * 4];
    float x;
    float4 c;
    x = a.x + b.x; x = (x > 0.f) ? x : 0.2f * x; c.x = __expf(x);
    x = a.y + b.y; x = (x > 0.f) ? x : 0.2f * x; c.y = __expf(x);
    x = a.z + b.z; x = (x > 0.f) ? x : 0.2f * x; c.z = __expf(x);
    x = a.w + b.w; x = (x > 0.f) ? x : 0.2f * x; c.w = __expf(x);
    uint4 rec;
    rec.x = (unsigned)s;
    rec.y = (unsigned)f2bf(c.x) | ((unsigned)f2bf(c.y) << 16);
    rec.z = (unsigned)f2bf(c.z) | ((unsigned)f2bf(c.w) << 16);
    rec.w = 0u;
    int pos = atomicAdd(&cursor[d], 1);
    recs[pos] = rec;
}

// ---------------- K6: gather: 32 lanes/node; cooperative denom; bf16 h; unroll 4
__global__ __launch_bounds__(256) void gather_agg_kernel(const int* __restrict__ base,
                                                         const int* __restrict__ cnt,
                                                         const uint4* __restrict__ recs,
                                                         const unsigned short* __restrict__ h16,
                                                         float* __restrict__ out) {
    int t = threadIdx.x;
    int node = blockIdx.x * 8 + (t >> 5);   // 8 nodes/block, 50000/8 = 6250 exact
    int ln = t & 31;
    int d0 = ln << 2;                        // 4 dims per lane
    int hh = ln >> 3;                        // head
    int q  = ln & 7;
    int o0 = base[node];
    int deg = cnt[node];
    int o1 = o0 + deg;

    // cooperative denom: 8 lanes/head read consecutive recs (128B/step per node group)
    float dsum = 0.f;
    for (int j = o0 + q; j < o1; j += 8) {
        uint4 r = recs[j];
        unsigned sel = (hh & 2) ? r.z : r.y;
        dsum += (hh & 1) ? bfh(sel) : bfl(sel);
    }
    dsum += __shfl_xor(dsum, 1, 64);
    dsum += __shfl_xor(dsum, 2, 64);
    dsum += __shfl_xor(dsum, 4, 64);
    float inv = (deg > 0) ? 1.0f / dsum : 0.f;

    size_t oidx = (size_t)node * 128 + d0;
    float4 acc = *(const float4*)&out[oidx];   // residual already there
    int j = o0;
    for (; j + 3 < o1; j += 4) {
        uint4 r0 = recs[j];
        uint4 r1 = recs[j + 1];
        uint4 r2 = recs[j + 2];
        uint4 r3 = recs[j + 3];
        unsigned s0 = (hh & 2) ? r0.z : r0.y; float a0 = ((hh & 1) ? bfh(s0) : bfl(s0)) * inv;
        unsigned s1 = (hh & 2) ? r1.z : r1.y; float a1 = ((hh & 1) ? bfh(s1) : bfl(s1)) * inv;
        unsigned s2 = (hh & 2) ? r2.z : r2.y; float a2 = ((hh & 1) ? bfh(s2) : bfl(s2)) * inv;
        unsigned s3 = (hh & 2) ? r3.z : r3.y; float a3 = ((hh & 1) ? bfh(s3) : bfl(s3)) * inv;
        uint2 h0 = *(const uint2*)&h16[(size_t)r0.x * 128 + d0];
        uint2 h1 = *(const uint2*)&h16[(size_t)r1.x * 128 + d0];
        uint2 h2 = *(const uint2*)&h16[(size_t)r2.x * 128 + d0];
        uint2 h3 = *(const uint2*)&h16[(size_t)r3.x * 128 + d0];
        acc.x = fmaf(a0, bfl(h0.x), acc.x); acc.y = fmaf(a0, bfh(h0.x), acc.y);
        acc.z = fmaf(a0, bfl(h0.y), acc.z); acc.w = fmaf(a0, bfh(h0.y), acc.w);
        acc.x = fmaf(a1, bfl(h1.x), acc.x); acc.y = fmaf(a1, bfh(h1.x), acc.y);
        acc.z = fmaf(a1, bfl(h1.y), acc.z); acc.w = fmaf(a1, bfh(h1.y), acc.w);
        acc.x = fmaf(a2, bfl(h2.x), acc.x); acc.y = fmaf(a2, bfh(h2.x), acc.y);
        acc.z = fmaf(a2, bfl(h2.y), acc.z); acc.w = fmaf(a2, bfh(h2.y), acc.w);
        acc.x = fmaf(a3, bfl(h3.x), acc.x); acc.y = fmaf(a3, bfh(h3.x), acc.y);
        acc.z = fmaf(a3, bfl(h3.y), acc.z); acc.w = fmaf(a3, bfh(h3.y), acc.w);
    }
    for (; j < o1; ++j) {
        uint4 r0 = recs[j];
        unsigned s0 = (hh & 2) ? r0.z : r0.y;
        float a0 = ((hh & 1) ? bfh(s0) : bfl(s0)) * inv;
        uint2 h0 = *(const uint2*)&h16[(size_t)r0.x * 128 + d0];
        acc.x = fmaf(a0, bfl(h0.x), acc.x); acc.y = fmaf(a0, bfh(h0.x), acc.y);
        acc.z = fmaf(a0, bfl(h0.y), acc.z); acc.w = fmaf(a0, bfh(h0.y), acc.w);
    }
    *(float4*)&out[oidx] = acc;
}

extern "C" void kernel_launch(void* const* d_in, const int* in_sizes, int n_in,
                              void* d_out, int out_size, void* d_ws, size_t ws_size,
                              hipStream_t stream) {
    const float* feat   = (const float*)d_in[0];
    const int*   src    = (const int*)d_in[1];
    const int*   dst    = (const int*)d_in[2];
    const float* fc_w   = (const float*)d_in[3];
    const float* attn_l = (const float*)d_in[4];
    const float* attn_r = (const float*)d_in[5];
    const float* res_w  = (const float*)d_in[6];
    float* out = (float*)d_out;

    // workspace layout (16B-aligned sections)
    unsigned short* h16 = (unsigned short*)d_ws;              // N*128 bf16 = 12.8 MB
    float* el  = (float*)(h16 + (size_t)NN * HDIM);           // N*4
    float* er  = el + (size_t)NN * HH;                        // N*4
    uint4* recs = (uint4*)(er + (size_t)NN * HH);             // E * 16B
    int*   cnt    = (int*)(recs + (size_t)EE);                // N
    int*   total  = cnt + NN;                                 // 1
    int*   base   = total + 1;                                // N
    int*   cursor = base + NN;                                // N

    dim3 ggrid(NN / 16, 4);
    mfma_gemm_kernel<<<ggrid, 256, 0, stream>>>(feat, fc_w, res_w, h16, out);

    elr_kernel<<<(NN * HDIM) / 256, 256, 0, stream>>>(h16, attn_l, attn_r, el, er, NN);

    hipMemsetAsync(cnt, 0, (size_t)(NN + 1) * sizeof(int), stream);  // cnt + total

    count_kernel<<<(EE + 255) / 256, 256, 0, stream>>>(dst, cnt, EE);

    seg_alloc_kernel<<<(NN + 255) / 256, 256, 0, stream>>>(cnt, base, cursor, total, NN);

    edge_scatter_kernel<<<(EE + 255) / 256, 256, 0, stream>>>(src, dst, el, er, cursor,
                                                              recs, EE);

    gather_agg_kernel<<<NN / 8, 256, 0, stream>>>(base, cnt, recs, h16, out);
}

// Round 7
// 177.029 us; speedup vs baseline: 1.3484x; 1.3484x over previous
//
#include <hip/hip_runtime.h>
#include <hip/hip_bf16.h>

#define NN 50000
#define EE 800000
#define HH 4
#define HDIM 128   // H*D

typedef __attribute__((ext_vector_type(8))) short bf16x8;
typedef __attribute__((ext_vector_type(4))) float f32x4;

__device__ inline unsigned short f2bf(float f) {
    unsigned u = __float_as_uint(f);
    u = u + 0x7FFFu + ((u >> 16) & 1u);   // round-to-nearest-even
    return (unsigned short)(u >> 16);
}
__device__ inline float bfl(unsigned u) { return __uint_as_float(u << 16); }
__device__ inline float bfh(unsigned u) { return __uint_as_float(u & 0xFFFF0000u); }

// ---------------- K1: MFMA bf16 GEMM, 64 rows x 256 cols per block.
// feat staged once as bf16 in LDS (pad +8 shorts); B (fc_w||res_w) held in
// per-wave register fragments (128KB total, L2-hot). 64 MFMAs per wave.
__global__ __launch_bounds__(256) void mfma_gemm_kernel(const float* __restrict__ feat,
                                                        const float* __restrict__ fc_w,
                                                        const float* __restrict__ res_w,
                                                        unsigned short* __restrict__ h16,
                                                        float* __restrict__ out,
                                                        int n) {
    __shared__ unsigned short As[64][136];   // 64 rows x 128 bf16, +8 pad (16B-aligned rows)
    int t = threadIdx.x;
    int w = t >> 6;          // wave 0..3 -> col block w*64
    int l = t & 63;
    int l15 = l & 15;
    int kg = l >> 4;         // 0..3
    int r0 = blockIdx.x * 64;
    int colbase = w * 64;

    // B fragments: bfrag[ct][ks], col = colbase + ct*16 + l15, k = ks*32 + kg*8 + j
    bf16x8 bfrag[4][4];
    #pragma unroll
    for (int ct = 0; ct < 4; ++ct) {
        int col = colbase + ct * 16 + l15;
        const float* wrow = (col < 128) ? &fc_w[(size_t)col * 128]
                                        : &res_w[(size_t)(col - 128) * 128];
        #pragma unroll
        for (int ks = 0; ks < 4; ++ks) {
            int k0 = ks * 32 + kg * 8;
            float4 b0 = *(const float4*)&wrow[k0];
            float4 b1 = *(const float4*)&wrow[k0 + 4];
            bf16x8 b;
            b[0] = (short)f2bf(b0.x); b[1] = (short)f2bf(b0.y);
            b[2] = (short)f2bf(b0.z); b[3] = (short)f2bf(b0.w);
            b[4] = (short)f2bf(b1.x); b[5] = (short)f2bf(b1.y);
            b[6] = (short)f2bf(b1.z); b[7] = (short)f2bf(b1.w);
            bfrag[ct][ks] = b;
        }
    }

    // stage feat 64x128 f32 -> bf16 LDS (each feat element fetched exactly once)
    for (int i = t; i < 64 * 32; i += 256) {
        int r = i >> 5;
        int c4 = (i & 31) << 2;
        float4 v = make_float4(0.f, 0.f, 0.f, 0.f);
        if (r0 + r < n) v = *(const float4*)&feat[(size_t)(r0 + r) * 128 + c4];
        unsigned short tmp[4] = { f2bf(v.x), f2bf(v.y), f2bf(v.z), f2bf(v.w) };
        *(uint2*)&As[r][c4] = *(uint2*)tmp;
    }
    __syncthreads();

    f32x4 acc[4][4];
    #pragma unroll
    for (int rt = 0; rt < 4; ++rt)
        #pragma unroll
        for (int ct = 0; ct < 4; ++ct)
            acc[rt][ct] = (f32x4){0.f, 0.f, 0.f, 0.f};

    #pragma unroll
    for (int ks = 0; ks < 4; ++ks) {
        bf16x8 afrag[4];
        #pragma unroll
        for (int rt = 0; rt < 4; ++rt)
            afrag[rt] = *(const bf16x8*)&As[rt * 16 + l15][ks * 32 + kg * 8];
        #pragma unroll
        for (int rt = 0; rt < 4; ++rt)
            #pragma unroll
            for (int ct = 0; ct < 4; ++ct)
                acc[rt][ct] = __builtin_amdgcn_mfma_f32_16x16x32_bf16(
                    afrag[rt], bfrag[ct][ks], acc[rt][ct], 0, 0, 0);
    }

    // epilogue: C/D layout col = l&15, row = 4*kg + reg  [m89]
    int rb = 4 * kg;
    if (w < 2) {               // h half -> bf16
        #pragma unroll
        for (int rt = 0; rt < 4; ++rt)
            #pragma unroll
            for (int ct = 0; ct < 4; ++ct)
                #pragma unroll
                for (int r = 0; r < 4; ++r) {
                    int row = r0 + rt * 16 + rb + r;
                    if (row < n)
                        h16[(size_t)row * 128 + colbase + ct * 16 + l15] = f2bf(acc[rt][ct][r]);
                }
    } else {                   // residual half -> f32 out
        #pragma unroll
        for (int rt = 0; rt < 4; ++rt)
            #pragma unroll
            for (int ct = 0; ct < 4; ++ct)
                #pragma unroll
                for (int r = 0; r < 4; ++r) {
                    int row = r0 + rt * 16 + rb + r;
                    if (row < n)
                        out[(size_t)row * 128 + (colbase - 128) + ct * 16 + l15] = acc[rt][ct][r];
                }
    }
}

// ---------------- K2: el/er from bf16 h
__global__ void elr_kernel(const unsigned short* __restrict__ h16,
                           const float* __restrict__ al,
                           const float* __restrict__ ar,
                           float* __restrict__ el,
                           float* __restrict__ er,
                           int n) {
    int idx = blockIdx.x * 256 + threadIdx.x;
    int node = idx >> 7;
    if (node >= n) return;
    int hd = idx & 127;
    float v = bfl((unsigned)h16[(size_t)node * 128 + hd]);
    float a = v * al[hd];
    float b = v * ar[hd];
    #pragma unroll
    for (int off = 16; off > 0; off >>= 1) {
        a += __shfl_down(a, off, 32);
        b += __shfl_down(b, off, 32);
    }
    if ((hd & 31) == 0) {
        el[node * 4 + (hd >> 5)] = a;
        er[node * 4 + (hd >> 5)] = b;
    }
}

// ---------------- K3: degree histogram
__global__ void count_kernel(const int* __restrict__ dst,
                             int* __restrict__ cnt,
                             int e) {
    int ed = blockIdx.x * 256 + threadIdx.x;
    if (ed >= e) return;
    atomicAdd(&cnt[dst[ed]], 1);
}

// ---------------- K4: per-node segment base via wave prefix + one atomic per wave
__global__ void seg_alloc_kernel(const int* __restrict__ cnt,
                                 int* __restrict__ base,
                                 int* __restrict__ cursor,
                                 int* __restrict__ total,
                                 int n) {
    int idx = blockIdx.x * 256 + threadIdx.x;
    int lane = threadIdx.x & 63;
    int c = (idx < n) ? cnt[idx] : 0;
    int pre = c;
    #pragma unroll
    for (int d = 1; d < 64; d <<= 1) {
        int v = __shfl_up(pre, d, 64);
        if (lane >= d) pre += v;
    }
    int wtot = __shfl(pre, 63, 64);
    int wbase = 0;
    if (lane == 63) wbase = atomicAdd(total, wtot);
    wbase = __shfl(wbase, 63, 64);
    if (idx < n) {
        int b = wbase + pre - c;
        base[idx] = b;
        cursor[idx] = b;
    }
}

// ---------------- K5: per-edge score + scatter one 16B record {src, bf16 c[4]}
__global__ void edge_scatter_kernel(const int* __restrict__ src,
                                    const int* __restrict__ dst,
                                    const float* __restrict__ el,
                                    const float* __restrict__ er,
                                    int* __restrict__ cursor,
                                    uint4* __restrict__ recs,
                                    int e) {
    int ed = blockIdx.x * 256 + threadIdx.x;
    if (ed >= e) return;
    int s = src[ed];
    int d = dst[ed];
    float4 a = *(const float4*)&el[(size_t)s * 4];
    float4 b = *(const float4*)&er[(size_t)d * 4];
    float x;
    float4 c;
    x = a.x + b.x; x = (x > 0.f) ? x : 0.2f * x; c.x = __expf(x);
    x = a.y + b.y; x = (x > 0.f) ? x : 0.2f * x; c.y = __expf(x);
    x = a.z + b.z; x = (x > 0.f) ? x : 0.2f * x; c.z = __expf(x);
    x = a.w + b.w; x = (x > 0.f) ? x : 0.2f * x; c.w = __expf(x);
    uint4 rec;
    rec.x = (unsigned)s;
    rec.y = (unsigned)f2bf(c.x) | ((unsigned)f2bf(c.y) << 16);
    rec.z = (unsigned)f2bf(c.z) | ((unsigned)f2bf(c.w) << 16);
    rec.w = 0u;
    int pos = atomicAdd(&cursor[d], 1);
    recs[pos] = rec;
}

// ---------------- K6: gather: 32 lanes/node; cooperative denom; bf16 h; unroll 4
__global__ __launch_bounds__(256) void gather_agg_kernel(const int* __restrict__ base,
                                                         const int* __restrict__ cnt,
                                                         const uint4* __restrict__ recs,
                                                         const unsigned short* __restrict__ h16,
                                                         float* __restrict__ out) {
    int t = threadIdx.x;
    int node = blockIdx.x * 8 + (t >> 5);   // 8 nodes/block, 50000/8 = 6250 exact
    int ln = t & 31;
    int d0 = ln << 2;                        // 4 dims per lane
    int hh = ln >> 3;                        // head
    int q  = ln & 7;
    int o0 = base[node];
    int deg = cnt[node];
    int o1 = o0 + deg;

    // cooperative denom: 8 lanes/head read consecutive recs (128B/step per node group)
    float dsum = 0.f;
    for (int j = o0 + q; j < o1; j += 8) {
        uint4 r = recs[j];
        unsigned sel = (hh & 2) ? r.z : r.y;
        dsum += (hh & 1) ? bfh(sel) : bfl(sel);
    }
    dsum += __shfl_xor(dsum, 1, 64);
    dsum += __shfl_xor(dsum, 2, 64);
    dsum += __shfl_xor(dsum, 4, 64);
    float inv = (deg > 0) ? 1.0f / dsum : 0.f;

    size_t oidx = (size_t)node * 128 + d0;
    float4 acc = *(const float4*)&out[oidx];   // residual already there
    int j = o0;
    for (; j + 3 < o1; j += 4) {
        uint4 r0 = recs[j];
        uint4 r1 = recs[j + 1];
        uint4 r2 = recs[j + 2];
        uint4 r3 = recs[j + 3];
        unsigned s0 = (hh & 2) ? r0.z : r0.y; float a0 = ((hh & 1) ? bfh(s0) : bfl(s0)) * inv;
        unsigned s1 = (hh & 2) ? r1.z : r1.y; float a1 = ((hh & 1) ? bfh(s1) : bfl(s1)) * inv;
        unsigned s2 = (hh & 2) ? r2.z : r2.y; float a2 = ((hh & 1) ? bfh(s2) : bfl(s2)) * inv;
        unsigned s3 = (hh & 2) ? r3.z : r3.y; float a3 = ((hh & 1) ? bfh(s3) : bfl(s3)) * inv;
        uint2 h0 = *(const uint2*)&h16[(size_t)r0.x * 128 + d0];
        uint2 h1 = *(const uint2*)&h16[(size_t)r1.x * 128 + d0];
        uint2 h2 = *(const uint2*)&h16[(size_t)r2.x * 128 + d0];
        uint2 h3 = *(const uint2*)&h16[(size_t)r3.x * 128 + d0];
        acc.x = fmaf(a0, bfl(h0.x), acc.x); acc.y = fmaf(a0, bfh(h0.x), acc.y);
        acc.z = fmaf(a0, bfl(h0.y), acc.z); acc.w = fmaf(a0, bfh(h0.y), acc.w);
        acc.x = fmaf(a1, bfl(h1.x), acc.x); acc.y = fmaf(a1, bfh(h1.x), acc.y);
        acc.z = fmaf(a1, bfl(h1.y), acc.z); acc.w = fmaf(a1, bfh(h1.y), acc.w);
        acc.x = fmaf(a2, bfl(h2.x), acc.x); acc.y = fmaf(a2, bfh(h2.x), acc.y);
        acc.z = fmaf(a2, bfl(h2.y), acc.z); acc.w = fmaf(a2, bfh(h2.y), acc.w);
        acc.x = fmaf(a3, bfl(h3.x), acc.x); acc.y = fmaf(a3, bfh(h3.x), acc.y);
        acc.z = fmaf(a3, bfl(h3.y), acc.z); acc.w = fmaf(a3, bfh(h3.y), acc.w);
    }
    for (; j < o1; ++j) {
        uint4 r0 = recs[j];
        unsigned s0 = (hh & 2) ? r0.z : r0.y;
        float a0 = ((hh & 1) ? bfh(s0) : bfl(s0)) * inv;
        uint2 h0 = *(const uint2*)&h16[(size_t)r0.x * 128 + d0];
        acc.x = fmaf(a0, bfl(h0.x), acc.x); acc.y = fmaf(a0, bfh(h0.x), acc.y);
        acc.z = fmaf(a0, bfl(h0.y), acc.z); acc.w = fmaf(a0, bfh(h0.y), acc.w);
    }
    *(float4*)&out[oidx] = acc;
}

extern "C" void kernel_launch(void* const* d_in, const int* in_sizes, int n_in,
                              void* d_out, int out_size, void* d_ws, size_t ws_size,
                              hipStream_t stream) {
    const float* feat   = (const float*)d_in[0];
    const int*   src    = (const int*)d_in[1];
    const int*   dst    = (const int*)d_in[2];
    const float* fc_w   = (const float*)d_in[3];
    const float* attn_l = (const float*)d_in[4];
    const float* attn_r = (const float*)d_in[5];
    const float* res_w  = (const float*)d_in[6];
    float* out = (float*)d_out;

    // workspace layout (16B-aligned sections)
    unsigned short* h16 = (unsigned short*)d_ws;              // N*128 bf16 = 12.8 MB
    float* el  = (float*)(h16 + (size_t)NN * HDIM);           // N*4
    float* er  = el + (size_t)NN * HH;                        // N*4
    uint4* recs = (uint4*)(er + (size_t)NN * HH);             // E * 16B
    int*   cnt    = (int*)(recs + (size_t)EE);                // N
    int*   total  = cnt + NN;                                 // 1
    int*   base   = total + 1;                                // N
    int*   cursor = base + NN;                                // N

    mfma_gemm_kernel<<<(NN + 63) / 64, 256, 0, stream>>>(feat, fc_w, res_w, h16, out, NN);

    elr_kernel<<<(NN * HDIM) / 256, 256, 0, stream>>>(h16, attn_l, attn_r, el, er, NN);

    hipMemsetAsync(cnt, 0, (size_t)(NN + 1) * sizeof(int), stream);  // cnt + total

    count_kernel<<<(EE + 255) / 256, 256, 0, stream>>>(dst, cnt, EE);

    seg_alloc_kernel<<<(NN + 255) / 256, 256, 0, stream>>>(cnt, base, cursor, total, NN);

    edge_scatter_kernel<<<(EE + 255) / 256, 256, 0, stream>>>(src, dst, el, er, cursor,
                                                              recs, EE);

    gather_agg_kernel<<<NN / 8, 256, 0, stream>>>(base, cnt, recs, h16, out);
}

// Round 8
// 149.680 us; speedup vs baseline: 1.5948x; 1.1827x over previous
//
#include <hip/hip_runtime.h>
#include <hip/hip_bf16.h>

#define NN 50000
#define EE 800000
#define HH 4
#define HDIM 128   // H*D
#define ELR_BLOCKS (NN * HDIM / 256)   // 25000
#define CNT_BLOCKS ((EE + 255) / 256)  // 3125

typedef __attribute__((ext_vector_type(8))) short bf16x8;
typedef __attribute__((ext_vector_type(4))) float f32x4;

__device__ inline unsigned short f2bf(float f) {
    unsigned u = __float_as_uint(f);
    u = u + 0x7FFFu + ((u >> 16) & 1u);   // round-to-nearest-even
    return (unsigned short)(u >> 16);
}
__device__ inline float bfl(unsigned u) { return __uint_as_float(u << 16); }
__device__ inline float bfh(unsigned u) { return __uint_as_float(u & 0xFFFF0000u); }

// ---------------- K1: MFMA bf16 GEMM, 64 rows x 256 cols per block.
__global__ __launch_bounds__(256) void mfma_gemm_kernel(const float* __restrict__ feat,
                                                        const float* __restrict__ fc_w,
                                                        const float* __restrict__ res_w,
                                                        unsigned short* __restrict__ h16,
                                                        float* __restrict__ out,
                                                        int n) {
    __shared__ unsigned short As[64][136];   // 64 rows x 128 bf16, +8 pad
    int t = threadIdx.x;
    int w = t >> 6;          // wave 0..3 -> col block w*64
    int l = t & 63;
    int l15 = l & 15;
    int kg = l >> 4;         // 0..3
    int r0 = blockIdx.x * 64;
    int colbase = w * 64;

    // B fragments: col = colbase + ct*16 + l15, k = ks*32 + kg*8 + j
    bf16x8 bfrag[4][4];
    #pragma unroll
    for (int ct = 0; ct < 4; ++ct) {
        int col = colbase + ct * 16 + l15;
        const float* wrow = (col < 128) ? &fc_w[(size_t)col * 128]
                                        : &res_w[(size_t)(col - 128) * 128];
        #pragma unroll
        for (int ks = 0; ks < 4; ++ks) {
            int k0 = ks * 32 + kg * 8;
            float4 b0 = *(const float4*)&wrow[k0];
            float4 b1 = *(const float4*)&wrow[k0 + 4];
            bf16x8 b;
            b[0] = (short)f2bf(b0.x); b[1] = (short)f2bf(b0.y);
            b[2] = (short)f2bf(b0.z); b[3] = (short)f2bf(b0.w);
            b[4] = (short)f2bf(b1.x); b[5] = (short)f2bf(b1.y);
            b[6] = (short)f2bf(b1.z); b[7] = (short)f2bf(b1.w);
            bfrag[ct][ks] = b;
        }
    }

    // stage feat 64x128 f32 -> bf16 LDS
    for (int i = t; i < 64 * 32; i += 256) {
        int r = i >> 5;
        int c4 = (i & 31) << 2;
        float4 v = make_float4(0.f, 0.f, 0.f, 0.f);
        if (r0 + r < n) v = *(const float4*)&feat[(size_t)(r0 + r) * 128 + c4];
        unsigned short tmp[4] = { f2bf(v.x), f2bf(v.y), f2bf(v.z), f2bf(v.w) };
        *(uint2*)&As[r][c4] = *(uint2*)tmp;
    }
    __syncthreads();

    f32x4 acc[4][4];
    #pragma unroll
    for (int rt = 0; rt < 4; ++rt)
        #pragma unroll
        for (int ct = 0; ct < 4; ++ct)
            acc[rt][ct] = (f32x4){0.f, 0.f, 0.f, 0.f};

    #pragma unroll
    for (int ks = 0; ks < 4; ++ks) {
        bf16x8 afrag[4];
        #pragma unroll
        for (int rt = 0; rt < 4; ++rt)
            afrag[rt] = *(const bf16x8*)&As[rt * 16 + l15][ks * 32 + kg * 8];
        #pragma unroll
        for (int rt = 0; rt < 4; ++rt)
            #pragma unroll
            for (int ct = 0; ct < 4; ++ct)
                acc[rt][ct] = __builtin_amdgcn_mfma_f32_16x16x32_bf16(
                    afrag[rt], bfrag[ct][ks], acc[rt][ct], 0, 0, 0);
    }

    // epilogue: C/D layout col = l&15, row = 4*kg + reg  [m89]
    int rb = 4 * kg;
    if (w < 2) {               // h half -> bf16
        #pragma unroll
        for (int rt = 0; rt < 4; ++rt)
            #pragma unroll
            for (int ct = 0; ct < 4; ++ct)
                #pragma unroll
                for (int r = 0; r < 4; ++r) {
                    int row = r0 + rt * 16 + rb + r;
                    if (row < n)
                        h16[(size_t)row * 128 + colbase + ct * 16 + l15] = f2bf(acc[rt][ct][r]);
                }
    } else {                   // residual half -> f32 out
        #pragma unroll
        for (int rt = 0; rt < 4; ++rt)
            #pragma unroll
            for (int ct = 0; ct < 4; ++ct)
                #pragma unroll
                for (int r = 0; r < 4; ++r) {
                    int row = r0 + rt * 16 + rb + r;
                    if (row < n)
                        out[(size_t)row * 128 + (colbase - 128) + ct * 16 + l15] = acc[rt][ct][r];
                }
    }
}

// ---------------- K2: fused: blocks [0,25000) el/er; blocks [25000,28125) degree+rank
__global__ void elr_count_kernel(const unsigned short* __restrict__ h16,
                                 const float* __restrict__ al,
                                 const float* __restrict__ ar,
                                 float* __restrict__ el,
                                 float* __restrict__ er,
                                 const int* __restrict__ dst,
                                 int* __restrict__ cnt,
                                 unsigned short* __restrict__ rank16) {
    int bx = blockIdx.x;
    int t = threadIdx.x;
    if (bx < ELR_BLOCKS) {
        int idx = bx * 256 + t;
        int node = idx >> 7;
        int hd = idx & 127;
        float v = bfl((unsigned)h16[(size_t)node * 128 + hd]);
        float a = v * al[hd];
        float b = v * ar[hd];
        #pragma unroll
        for (int off = 16; off > 0; off >>= 1) {
            a += __shfl_down(a, off, 32);
            b += __shfl_down(b, off, 32);
        }
        if ((hd & 31) == 0) {
            el[node * 4 + (hd >> 5)] = a;
            er[node * 4 + (hd >> 5)] = b;
        }
    } else {
        int ed = (bx - ELR_BLOCKS) * 256 + t;
        if (ed < EE) {
            int d = dst[ed];
            int r = atomicAdd(&cnt[d], 1);
            rank16[ed] = (unsigned short)r;
        }
    }
}

// ---------------- K3: per-node segment base via wave prefix + one atomic per wave
__global__ void seg_alloc_kernel(const int* __restrict__ cnt,
                                 int* __restrict__ base,
                                 int* __restrict__ total,
                                 int n) {
    int idx = blockIdx.x * 256 + threadIdx.x;
    int lane = threadIdx.x & 63;
    int c = (idx < n) ? cnt[idx] : 0;
    int pre = c;
    #pragma unroll
    for (int d = 1; d < 64; d <<= 1) {
        int v = __shfl_up(pre, d, 64);
        if (lane >= d) pre += v;
    }
    int wtot = __shfl(pre, 63, 64);
    int wbase = 0;
    if (lane == 63) wbase = atomicAdd(total, wtot);
    wbase = __shfl(wbase, 63, 64);
    if (idx < n) base[idx] = wbase + pre - c;
}

// ---------------- K4: place src into CSR slot (no atomics)
__global__ void place_kernel(const int* __restrict__ src,
                             const int* __restrict__ dst,
                             const int* __restrict__ base,
                             const unsigned short* __restrict__ rank16,
                             int* __restrict__ perm_src,
                             int e) {
    int ed = blockIdx.x * 256 + threadIdx.x;
    if (ed >= e) return;
    int d = dst[ed];
    int pos = base[d] + (int)rank16[ed];
    perm_src[pos] = src[ed];
}

// ---------------- K5: gather: 32 lanes/node; recompute coeff from el/er; bf16 h
__global__ __launch_bounds__(256) void gather_agg_kernel(const int* __restrict__ base,
                                                         const int* __restrict__ cnt,
                                                         const int* __restrict__ perm_src,
                                                         const float* __restrict__ el,
                                                         const float* __restrict__ er,
                                                         const unsigned short* __restrict__ h16,
                                                         float* __restrict__ out) {
    int t = threadIdx.x;
    int node = blockIdx.x * 8 + (t >> 5);   // 8 nodes/block, 50000/8 = 6250 exact
    int ln = t & 31;
    int d0 = ln << 2;                        // 4 dims per lane
    int hh = ln >> 3;                        // head
    int q  = ln & 7;
    int o0 = base[node];
    int deg = cnt[node];
    int o1 = o0 + deg;
    float erh = er[node * 4 + hh];

    // cooperative denom: 8 lanes/head, stride-8 over segment; recompute coeff
    float dsum = 0.f;
    for (int j = o0 + q; j < o1; j += 8) {
        int s = perm_src[j];
        float x = el[s * 4 + hh] + erh;
        x = (x > 0.f) ? x : 0.2f * x;
        dsum += __expf(x);
    }
    dsum += __shfl_xor(dsum, 1, 64);
    dsum += __shfl_xor(dsum, 2, 64);
    dsum += __shfl_xor(dsum, 4, 64);
    float inv = (deg > 0) ? 1.0f / dsum : 0.f;

    size_t oidx = (size_t)node * 128 + d0;
    float4 acc = *(const float4*)&out[oidx];   // residual already there
    int j = o0;
    for (; j + 3 < o1; j += 4) {
        int s0 = perm_src[j];
        int s1 = perm_src[j + 1];
        int s2 = perm_src[j + 2];
        int s3 = perm_src[j + 3];
        float x0 = el[s0 * 4 + hh] + erh; x0 = (x0 > 0.f) ? x0 : 0.2f * x0;
        float x1 = el[s1 * 4 + hh] + erh; x1 = (x1 > 0.f) ? x1 : 0.2f * x1;
        float x2 = el[s2 * 4 + hh] + erh; x2 = (x2 > 0.f) ? x2 : 0.2f * x2;
        float x3 = el[s3 * 4 + hh] + erh; x3 = (x3 > 0.f) ? x3 : 0.2f * x3;
        float a0 = __expf(x0) * inv;
        float a1 = __expf(x1) * inv;
        float a2 = __expf(x2) * inv;
        float a3 = __expf(x3) * inv;
        uint2 h0 = *(const uint2*)&h16[(size_t)s0 * 128 + d0];
        uint2 h1 = *(const uint2*)&h16[(size_t)s1 * 128 + d0];
        uint2 h2 = *(const uint2*)&h16[(size_t)s2 * 128 + d0];
        uint2 h3 = *(const uint2*)&h16[(size_t)s3 * 128 + d0];
        acc.x = fmaf(a0, bfl(h0.x), acc.x); acc.y = fmaf(a0, bfh(h0.x), acc.y);
        acc.z = fmaf(a0, bfl(h0.y), acc.z); acc.w = fmaf(a0, bfh(h0.y), acc.w);
        acc.x = fmaf(a1, bfl(h1.x), acc.x); acc.y = fmaf(a1, bfh(h1.x), acc.y);
        acc.z = fmaf(a1, bfl(h1.y), acc.z); acc.w = fmaf(a1, bfh(h1.y), acc.w);
        acc.x = fmaf(a2, bfl(h2.x), acc.x); acc.y = fmaf(a2, bfh(h2.x), acc.y);
        acc.z = fmaf(a2, bfl(h2.y), acc.z); acc.w = fmaf(a2, bfh(h2.y), acc.w);
        acc.x = fmaf(a3, bfl(h3.x), acc.x); acc.y = fmaf(a3, bfh(h3.x), acc.y);
        acc.z = fmaf(a3, bfl(h3.y), acc.z); acc.w = fmaf(a3, bfh(h3.y), acc.w);
    }
    for (; j < o1; ++j) {
        int s0 = perm_src[j];
        float x0 = el[s0 * 4 + hh] + erh; x0 = (x0 > 0.f) ? x0 : 0.2f * x0;
        float a0 = __expf(x0) * inv;
        uint2 h0 = *(const uint2*)&h16[(size_t)s0 * 128 + d0];
        acc.x = fmaf(a0, bfl(h0.x), acc.x); acc.y = fmaf(a0, bfh(h0.x), acc.y);
        acc.z = fmaf(a0, bfl(h0.y), acc.z); acc.w = fmaf(a0, bfh(h0.y), acc.w);
    }
    *(float4*)&out[oidx] = acc;
}

extern "C" void kernel_launch(void* const* d_in, const int* in_sizes, int n_in,
                              void* d_out, int out_size, void* d_ws, size_t ws_size,
                              hipStream_t stream) {
    const float* feat   = (const float*)d_in[0];
    const int*   src    = (const int*)d_in[1];
    const int*   dst    = (const int*)d_in[2];
    const float* fc_w   = (const float*)d_in[3];
    const float* attn_l = (const float*)d_in[4];
    const float* attn_r = (const float*)d_in[5];
    const float* res_w  = (const float*)d_in[6];
    float* out = (float*)d_out;

    // workspace layout (16B-aligned sections)
    unsigned short* h16 = (unsigned short*)d_ws;              // N*128 bf16 = 12.8 MB
    float* el  = (float*)(h16 + (size_t)NN * HDIM);           // N*4
    float* er  = el + (size_t)NN * HH;                        // N*4
    int*   perm_src = (int*)(er + (size_t)NN * HH);           // E
    unsigned short* rank16 = (unsigned short*)(perm_src + EE);// E (2B)
    int*   cnt    = (int*)(rank16 + EE);                      // N
    int*   total  = cnt + NN;                                 // 1
    int*   base   = total + 1;                                // N

    mfma_gemm_kernel<<<(NN + 63) / 64, 256, 0, stream>>>(feat, fc_w, res_w, h16, out, NN);

    hipMemsetAsync(cnt, 0, (size_t)(NN + 1) * sizeof(int), stream);  // cnt + total

    elr_count_kernel<<<ELR_BLOCKS + CNT_BLOCKS, 256, 0, stream>>>(h16, attn_l, attn_r,
                                                                  el, er, dst, cnt, rank16);

    seg_alloc_kernel<<<(NN + 255) / 256, 256, 0, stream>>>(cnt, base, total, NN);

    place_kernel<<<CNT_BLOCKS, 256, 0, stream>>>(src, dst, base, rank16, perm_src, EE);

    gather_agg_kernel<<<NN / 8, 256, 0, stream>>>(base, cnt, perm_src, el, er, h16, out);
}

// Round 9
// 134.530 us; speedup vs baseline: 1.7744x; 1.1126x over previous
//
#include <hip/hip_runtime.h>
#include <hip/hip_bf16.h>

#define NN 50000
#define EE 800000
#define HH 4
#define HDIM 128   // H*D

#define GEMM_BLOCKS ((NN + 63) / 64)        // 782
#define CNT_BLOCKS  ((EE + 255) / 256)      // 3125
#define ELR_BLOCKS  ((NN * HH + 255) / 256) // 782
#define SEG_BLOCKS  ((NN + 255) / 256)      // 196

typedef __attribute__((ext_vector_type(8))) short bf16x8;
typedef __attribute__((ext_vector_type(4))) float f32x4;

__device__ inline unsigned short f2bf(float f) {
    unsigned u = __float_as_uint(f);
    u = u + 0x7FFFu + ((u >> 16) & 1u);   // round-to-nearest-even
    return (unsigned short)(u >> 16);
}
__device__ inline float bfl(unsigned u) { return __uint_as_float(u << 16); }
__device__ inline float bfh(unsigned u) { return __uint_as_float(u & 0xFFFF0000u); }

// ---------------- K1: blocks [0,782): MFMA bf16 GEMM 64 rows x 256 cols.
//                     blocks [782, 782+3125): degree count + rank (independent, hides under GEMM)
__global__ __launch_bounds__(256) void gemm_count_kernel(const float* __restrict__ feat,
                                                         const float* __restrict__ fc_w,
                                                         const float* __restrict__ res_w,
                                                         unsigned short* __restrict__ h16,
                                                         float* __restrict__ out,
                                                         const int* __restrict__ dst,
                                                         int* __restrict__ cnt,
                                                         unsigned short* __restrict__ rank16,
                                                         int n) {
    if (blockIdx.x >= GEMM_BLOCKS) {
        int ed = (blockIdx.x - GEMM_BLOCKS) * 256 + threadIdx.x;
        if (ed < EE) {
            int d = dst[ed];
            rank16[ed] = (unsigned short)atomicAdd(&cnt[d], 1);
        }
        return;
    }

    __shared__ unsigned short As[64][136];   // 64 rows x 128 bf16, +8 pad
    int t = threadIdx.x;
    int w = t >> 6;          // wave 0..3 -> col block w*64
    int l = t & 63;
    int l15 = l & 15;
    int kg = l >> 4;         // 0..3
    int r0 = blockIdx.x * 64;
    int colbase = w * 64;

    // B fragments: col = colbase + ct*16 + l15, k = ks*32 + kg*8 + j
    bf16x8 bfrag[4][4];
    #pragma unroll
    for (int ct = 0; ct < 4; ++ct) {
        int col = colbase + ct * 16 + l15;
        const float* wrow = (col < 128) ? &fc_w[(size_t)col * 128]
                                        : &res_w[(size_t)(col - 128) * 128];
        #pragma unroll
        for (int ks = 0; ks < 4; ++ks) {
            int k0 = ks * 32 + kg * 8;
            float4 b0 = *(const float4*)&wrow[k0];
            float4 b1 = *(const float4*)&wrow[k0 + 4];
            bf16x8 b;
            b[0] = (short)f2bf(b0.x); b[1] = (short)f2bf(b0.y);
            b[2] = (short)f2bf(b0.z); b[3] = (short)f2bf(b0.w);
            b[4] = (short)f2bf(b1.x); b[5] = (short)f2bf(b1.y);
            b[6] = (short)f2bf(b1.z); b[7] = (short)f2bf(b1.w);
            bfrag[ct][ks] = b;
        }
    }

    // stage feat 64x128 f32 -> bf16 LDS
    for (int i = t; i < 64 * 32; i += 256) {
        int r = i >> 5;
        int c4 = (i & 31) << 2;
        float4 v = make_float4(0.f, 0.f, 0.f, 0.f);
        if (r0 + r < n) v = *(const float4*)&feat[(size_t)(r0 + r) * 128 + c4];
        unsigned short tmp[4] = { f2bf(v.x), f2bf(v.y), f2bf(v.z), f2bf(v.w) };
        *(uint2*)&As[r][c4] = *(uint2*)tmp;
    }
    __syncthreads();

    f32x4 acc[4][4];
    #pragma unroll
    for (int rt = 0; rt < 4; ++rt)
        #pragma unroll
        for (int ct = 0; ct < 4; ++ct)
            acc[rt][ct] = (f32x4){0.f, 0.f, 0.f, 0.f};

    #pragma unroll
    for (int ks = 0; ks < 4; ++ks) {
        bf16x8 afrag[4];
        #pragma unroll
        for (int rt = 0; rt < 4; ++rt)
            afrag[rt] = *(const bf16x8*)&As[rt * 16 + l15][ks * 32 + kg * 8];
        #pragma unroll
        for (int rt = 0; rt < 4; ++rt)
            #pragma unroll
            for (int ct = 0; ct < 4; ++ct)
                acc[rt][ct] = __builtin_amdgcn_mfma_f32_16x16x32_bf16(
                    afrag[rt], bfrag[ct][ks], acc[rt][ct], 0, 0, 0);
    }

    // epilogue: C/D layout col = l&15, row = 4*kg + reg  [m89]
    int rb = 4 * kg;
    if (w < 2) {               // h half -> bf16
        #pragma unroll
        for (int rt = 0; rt < 4; ++rt)
            #pragma unroll
            for (int ct = 0; ct < 4; ++ct)
                #pragma unroll
                for (int r = 0; r < 4; ++r) {
                    int row = r0 + rt * 16 + rb + r;
                    if (row < n)
                        h16[(size_t)row * 128 + colbase + ct * 16 + l15] = f2bf(acc[rt][ct][r]);
                }
    } else {                   // residual half -> f32 out
        #pragma unroll
        for (int rt = 0; rt < 4; ++rt)
            #pragma unroll
            for (int ct = 0; ct < 4; ++ct)
                #pragma unroll
                for (int r = 0; r < 4; ++r) {
                    int row = r0 + rt * 16 + rb + r;
                    if (row < n)
                        out[(size_t)row * 128 + (colbase - 128) + ct * 16 + l15] = acc[rt][ct][r];
                }
    }
}

// ---------------- K2: blocks [0,782): el/er, 1 thread per (node,head), uint4 loads.
//                     blocks [782,782+196): seg_alloc (base from cnt).
__global__ void elr_seg_kernel(const unsigned short* __restrict__ h16,
                               const float* __restrict__ al,
                               const float* __restrict__ ar,
                               float* __restrict__ el,
                               float* __restrict__ er,
                               const int* __restrict__ cnt,
                               int* __restrict__ base,
                               int* __restrict__ total) {
    int bx = blockIdx.x;
    int t = threadIdx.x;
    if (bx < ELR_BLOCKS) {
        int idx = bx * 256 + t;
        if (idx >= NN * HH) return;
        int node = idx >> 2;
        int hh = idx & 3;
        const unsigned short* hp = &h16[(size_t)node * 128 + hh * 32];
        const float* alp = &al[hh * 32];
        const float* arp = &ar[hh * 32];
        float a = 0.f, b = 0.f;
        #pragma unroll
        for (int c = 0; c < 4; ++c) {           // 4 x uint4 = 32 bf16
            uint4 hv = *(const uint4*)&hp[c * 8];
            unsigned uu[4] = { hv.x, hv.y, hv.z, hv.w };
            #pragma unroll
            for (int j = 0; j < 4; ++j) {
                float v0 = bfl(uu[j]);
                float v1 = bfh(uu[j]);
                int d = c * 8 + j * 2;
                a = fmaf(v0, alp[d], a);     a = fmaf(v1, alp[d + 1], a);
                b = fmaf(v0, arp[d], b);     b = fmaf(v1, arp[d + 1], b);
            }
        }
        el[idx] = a;
        er[idx] = b;
    } else {
        int idx = (bx - ELR_BLOCKS) * 256 + t;
        int lane = t & 63;
        int c = (idx < NN) ? cnt[idx] : 0;
        int pre = c;
        #pragma unroll
        for (int d = 1; d < 64; d <<= 1) {
            int v = __shfl_up(pre, d, 64);
            if (lane >= d) pre += v;
        }
        int wtot = __shfl(pre, 63, 64);
        int wbase = 0;
        if (lane == 63) wbase = atomicAdd(total, wtot);
        wbase = __shfl(wbase, 63, 64);
        if (idx < NN) base[idx] = wbase + pre - c;
    }
}

// ---------------- K3: place src into CSR slot (no atomics)
__global__ void place_kernel(const int* __restrict__ src,
                             const int* __restrict__ dst,
                             const int* __restrict__ base,
                             const unsigned short* __restrict__ rank16,
                             int* __restrict__ perm_src,
                             int e) {
    int ed = blockIdx.x * 256 + threadIdx.x;
    if (ed >= e) return;
    int d = dst[ed];
    int pos = base[d] + (int)rank16[ed];
    perm_src[pos] = src[ed];
}

// ---------------- K4: gather: 32 lanes/node; recompute coeff from el/er; bf16 h
__global__ __launch_bounds__(256) void gather_agg_kernel(const int* __restrict__ base,
                                                         const int* __restrict__ cnt,
                                                         const int* __restrict__ perm_src,
                                                         const float* __restrict__ el,
                                                         const float* __restrict__ er,
                                                         const unsigned short* __restrict__ h16,
                                                         float* __restrict__ out) {
    int t = threadIdx.x;
    int node = blockIdx.x * 8 + (t >> 5);   // 8 nodes/block, 50000/8 = 6250 exact
    int ln = t & 31;
    int d0 = ln << 2;                        // 4 dims per lane
    int hh = ln >> 3;                        // head
    int q  = ln & 7;
    int o0 = base[node];
    int deg = cnt[node];
    int o1 = o0 + deg;
    float erh = er[node * 4 + hh];

    // cooperative denom: 8 lanes/head, stride-8 over segment; recompute coeff
    float dsum = 0.f;
    for (int j = o0 + q; j < o1; j += 8) {
        int s = perm_src[j];
        float x = el[s * 4 + hh] + erh;
        x = (x > 0.f) ? x : 0.2f * x;
        dsum += __expf(x);
    }
    dsum += __shfl_xor(dsum, 1, 64);
    dsum += __shfl_xor(dsum, 2, 64);
    dsum += __shfl_xor(dsum, 4, 64);
    float inv = (deg > 0) ? 1.0f / dsum : 0.f;

    size_t oidx = (size_t)node * 128 + d0;
    float4 acc = *(const float4*)&out[oidx];   // residual already there
    int j = o0;
    for (; j + 3 < o1; j += 4) {
        int s0 = perm_src[j];
        int s1 = perm_src[j + 1];
        int s2 = perm_src[j + 2];
        int s3 = perm_src[j + 3];
        float x0 = el[s0 * 4 + hh] + erh; x0 = (x0 > 0.f) ? x0 : 0.2f * x0;
        float x1 = el[s1 * 4 + hh] + erh; x1 = (x1 > 0.f) ? x1 : 0.2f * x1;
        float x2 = el[s2 * 4 + hh] + erh; x2 = (x2 > 0.f) ? x2 : 0.2f * x2;
        float x3 = el[s3 * 4 + hh] + erh; x3 = (x3 > 0.f) ? x3 : 0.2f * x3;
        float a0 = __expf(x0) * inv;
        float a1 = __expf(x1) * inv;
        float a2 = __expf(x2) * inv;
        float a3 = __expf(x3) * inv;
        uint2 h0 = *(const uint2*)&h16[(size_t)s0 * 128 + d0];
        uint2 h1 = *(const uint2*)&h16[(size_t)s1 * 128 + d0];
        uint2 h2 = *(const uint2*)&h16[(size_t)s2 * 128 + d0];
        uint2 h3 = *(const uint2*)&h16[(size_t)s3 * 128 + d0];
        acc.x = fmaf(a0, bfl(h0.x), acc.x); acc.y = fmaf(a0, bfh(h0.x), acc.y);
        acc.z = fmaf(a0, bfl(h0.y), acc.z); acc.w = fmaf(a0, bfh(h0.y), acc.w);
        acc.x = fmaf(a1, bfl(h1.x), acc.x); acc.y = fmaf(a1, bfh(h1.x), acc.y);
        acc.z = fmaf(a1, bfl(h1.y), acc.z); acc.w = fmaf(a1, bfh(h1.y), acc.w);
        acc.x = fmaf(a2, bfl(h2.x), acc.x); acc.y = fmaf(a2, bfh(h2.x), acc.y);
        acc.z = fmaf(a2, bfl(h2.y), acc.z); acc.w = fmaf(a2, bfh(h2.y), acc.w);
        acc.x = fmaf(a3, bfl(h3.x), acc.x); acc.y = fmaf(a3, bfh(h3.x), acc.y);
        acc.z = fmaf(a3, bfl(h3.y), acc.z); acc.w = fmaf(a3, bfh(h3.y), acc.w);
    }
    for (; j < o1; ++j) {
        int s0 = perm_src[j];
        float x0 = el[s0 * 4 + hh] + erh; x0 = (x0 > 0.f) ? x0 : 0.2f * x0;
        float a0 = __expf(x0) * inv;
        uint2 h0 = *(const uint2*)&h16[(size_t)s0 * 128 + d0];
        acc.x = fmaf(a0, bfl(h0.x), acc.x); acc.y = fmaf(a0, bfh(h0.x), acc.y);
        acc.z = fmaf(a0, bfl(h0.y), acc.z); acc.w = fmaf(a0, bfh(h0.y), acc.w);
    }
    *(float4*)&out[oidx] = acc;
}

extern "C" void kernel_launch(void* const* d_in, const int* in_sizes, int n_in,
                              void* d_out, int out_size, void* d_ws, size_t ws_size,
                              hipStream_t stream) {
    const float* feat   = (const float*)d_in[0];
    const int*   src    = (const int*)d_in[1];
    const int*   dst    = (const int*)d_in[2];
    const float* fc_w   = (const float*)d_in[3];
    const float* attn_l = (const float*)d_in[4];
    const float* attn_r = (const float*)d_in[5];
    const float* res_w  = (const float*)d_in[6];
    float* out = (float*)d_out;

    // workspace layout (16B-aligned sections)
    unsigned short* h16 = (unsigned short*)d_ws;              // N*128 bf16 = 12.8 MB
    float* el  = (float*)(h16 + (size_t)NN * HDIM);           // N*4
    float* er  = el + (size_t)NN * HH;                        // N*4
    int*   perm_src = (int*)(er + (size_t)NN * HH);           // E
    unsigned short* rank16 = (unsigned short*)(perm_src + EE);// E (2B)
    int*   cnt    = (int*)(rank16 + EE);                      // N
    int*   total  = cnt + NN;                                 // 1
    int*   base   = total + 1;                                // N

    // zero cnt + total BEFORE the fused gemm+count dispatch
    hipMemsetAsync(cnt, 0, (size_t)(NN + 1) * sizeof(int), stream);

    gemm_count_kernel<<<GEMM_BLOCKS + CNT_BLOCKS, 256, 0, stream>>>(
        feat, fc_w, res_w, h16, out, dst, cnt, rank16, NN);

    elr_seg_kernel<<<ELR_BLOCKS + SEG_BLOCKS, 256, 0, stream>>>(
        h16, attn_l, attn_r, el, er, cnt, base, total);

    place_kernel<<<CNT_BLOCKS, 256, 0, stream>>>(src, dst, base, rank16, perm_src, EE);

    gather_agg_kernel<<<NN / 8, 256, 0, stream>>>(base, cnt, perm_src, el, er, h16, out);
}